// Round 15
// baseline (708.239 us; speedup 1.0000x reference)
//
#include <hip/hip_runtime.h>
#include <hip/hip_bf16.h>

#define B_ 4
#define L_ 2048
#define D_ 1024
#define H_ 4
#define DK_ 256
#define DV_ 256
#define NCH 64
#define NTOK 8192

typedef __attribute__((ext_vector_type(8))) short bf16x8;
typedef __attribute__((ext_vector_type(4))) float f32x4;
typedef unsigned int u32;

__device__ __forceinline__ float bu2f(unsigned short u) {
    union { unsigned int i; float f; } x; x.i = ((unsigned int)u) << 16; return x.f;
}
__device__ __forceinline__ unsigned short f2bu(float f) {
    union { __hip_bfloat16 h; unsigned short u; } x; x.h = __float2bfloat16(f); return x.u;
}
#define MFMA16(a, b, c) __builtin_amdgcn_mfma_f32_16x16x32_bf16(a, b, c, 0, 0, 0)

__device__ __forceinline__ void gload16(const void* g, void* l) {
    __builtin_amdgcn_global_load_lds(
        (const __attribute__((address_space(1))) u32*)g,
        (__attribute__((address_space(3))) u32*)l, 16, 0, 0);
}

// Raw barrier: orders LDS (lgkmcnt only) + s_barrier; no vmcnt drain.
#define RAWBAR() { asm volatile("s_waitcnt lgkmcnt(0)" ::: "memory"); \
    __builtin_amdgcn_sched_barrier(0); \
    __builtin_amdgcn_s_barrier(); \
    __builtin_amdgcn_sched_barrier(0); }

// Fenced barrier (no waitcnt at all): scheduling-pinned s_barrier.
#define GBAR() { __builtin_amdgcn_sched_barrier(0); \
    __builtin_amdgcn_s_barrier(); \
    __builtin_amdgcn_sched_barrier(0); }

// counted vmcnt, tail-aware: steady 8 (2 half-tiles in flight), tail 4, 0
#define RING_WAIT(s, S) { \
    if ((s) + 3 < (S))      { asm volatile("s_waitcnt vmcnt(8)" ::: "memory"); } \
    else if ((s) + 2 < (S)) { asm volatile("s_waitcnt vmcnt(4)" ::: "memory"); } \
    else if ((s) + 1 < (S)) { asm volatile("s_waitcnt vmcnt(0)" ::: "memory"); } \
    __builtin_amdgcn_sched_barrier(0); }

// ---------------------------------------------------------------- transpose fp32 -> bf16, out[n][k] = in[k][n]
__global__ __launch_bounds__(256) void k_transpose(const float* __restrict__ in,
                                                   unsigned short* __restrict__ out,
                                                   int K, int N) {
    __shared__ float tile[32][33];
    int k0 = blockIdx.y * 32, n0 = blockIdx.x * 32;
    int tx = threadIdx.x & 31, ty = threadIdx.x >> 5;  // 32 x 8
#pragma unroll
    for (int r = 0; r < 4; ++r)
        tile[ty + 8 * r][tx] = in[(long)(k0 + ty + 8 * r) * N + n0 + tx];
    __syncthreads();
#pragma unroll
    for (int r = 0; r < 4; ++r)
        out[(long)(n0 + ty + 8 * r) * K + k0 + tx] = f2bu(tile[tx][ty + 8 * r]);
}

// W_fuse2 [2048][16] -> padded transpose [128][2048] bf16 (rows >=16 zero)
__global__ __launch_bounds__(256) void k_padT2(const float* __restrict__ W,
                                               unsigned short* __restrict__ out) {
    long idx = (long)blockIdx.x * 256 + threadIdx.x;  // 128*2048
    int n = (int)(idx >> 11), k = (int)(idx & 2047);
    out[idx] = (n < 16) ? f2bu(W[k * 16 + n]) : (unsigned short)0;
}

// hidden_states fp32 -> gate_in[:, 0:1024] bf16 (row stride 4096) + beta
__global__ __launch_bounds__(256) void k_cvt_beta(const float4* __restrict__ hs4,
                                                  const float* __restrict__ W_b,
                                                  unsigned short* __restrict__ gate_in,
                                                  float* __restrict__ beta) {
    int tok = blockIdx.x;
    int tid = threadIdx.x;
    float4 v = hs4[(long)tok * 256 + tid];
    ushort4 o;
    o.x = f2bu(v.x); o.y = f2bu(v.y); o.z = f2bu(v.z); o.w = f2bu(v.w);
    *reinterpret_cast<ushort4*>(&gate_in[(long)tok * 4096 + tid * 4]) = o;
    const float4* wb = reinterpret_cast<const float4*>(W_b);  // [1024] rows
    int c4 = tid * 4;
    float4 w0 = wb[c4], w1 = wb[c4 + 1], w2 = wb[c4 + 2], w3 = wb[c4 + 3];
    float s[4];
    s[0] = v.x * w0.x + v.y * w1.x + v.z * w2.x + v.w * w3.x;
    s[1] = v.x * w0.y + v.y * w1.y + v.z * w2.y + v.w * w3.y;
    s[2] = v.x * w0.z + v.y * w1.z + v.z * w2.z + v.w * w3.z;
    s[3] = v.x * w0.w + v.y * w1.w + v.z * w2.w + v.w * w3.w;
    int wave = tid >> 6, lane = tid & 63;
#pragma unroll
    for (int off = 32; off; off >>= 1)
#pragma unroll
        for (int h = 0; h < 4; ++h) s[h] += __shfl_down(s[h], off);
    __shared__ float red[4][4];
    if (lane == 0)
#pragma unroll
        for (int h = 0; h < 4; ++h) red[wave][h] = s[h];
    __syncthreads();
    if (tid < 4) {
        int h = tid;
        float tot = red[0][h] + red[1][h] + red[2][h] + red[3][h];
        int b = tok >> 11, l = tok & 2047;
        beta[((long)(b * H_ + h)) * L_ + l] = 1.f / (1.f + expf(-tot));
    }
}

// ---------------------------------------------------------------- main GEMM: C = A[M,K] * BT[N,K]^T
// 128x128 ring GEMM (T2-corrected + T4 counted vmcnt): 4-slot LDS ring of
// BK=32 slices (64KB). Per phase: stage slot s+3 (4 gload16/wave), read 8
// frags from slot s, 16 MFMA, counted vmcnt(8) (loads stay in flight across
// the fenced barrier - no drain). Swizzle for 64B rows: read group
// lg ^ ((row>>1)&3) [<=2-way banks]; source pre-swizzle (l&3)^((l>>3)&3).
// EPI: 0 = fp32 out, 1 = bf16 out, 2 = bf16 out with bias+gelu(exact)
template <int EPI>
__global__ __launch_bounds__(256, 2) void k_gemm(const unsigned short* __restrict__ A, int lda,
                                                 const unsigned short* __restrict__ BT, int ldb,
                                                 void* __restrict__ Cout, int ldc,
                                                 const float* __restrict__ bias,
                                                 int K, int gx) {
    __shared__ __align__(16) unsigned short As[4][128][32];
    __shared__ __align__(16) unsigned short Bs[4][128][32];
    const int tid = threadIdx.x;
    const int wave = tid >> 6, lane = tid & 63;
    const int wm = wave & 1, wn = wave >> 1;
    const int lr = lane & 15, lg = lane >> 4;
    const int nwg = gridDim.x;
    const int cpx = nwg >> 3;
    const int orig = blockIdx.x;
    const int wg = (orig & 7) * cpx + (orig >> 3);
    const int m0 = (wg / gx) * 128, n0 = (wg % gx) * 128;
    // staging: one gload16 = 16 rows x 32 cols (1KB); wave w covers rows
    // [w*16, w*16+16) and [64+w*16, ...). lane l: row=l>>2, src group
    // pre-swizzled (l&3)^((l>>3)&3) so linear LDS holds swizzled layout.
    const int srow = lane >> 2;
    const int sg = ((lane & 3) ^ ((lane >> 3) & 3)) * 8;
    const unsigned short* Ag0 = A + (long)(m0 + wave * 16 + srow) * lda + sg;
    const unsigned short* Ag1 = Ag0 + (long)64 * lda;
    const unsigned short* Bg0 = BT + (long)(n0 + wave * 16 + srow) * ldb + sg;
    const unsigned short* Bg1 = Bg0 + (long)64 * ldb;
    const int S = K >> 5;
    const int gsw = (lg ^ ((lr >> 1) & 3)) * 8;   // read group (row parity via lr)
    f32x4 acc[4][4] = {};

#define STG(sidx) { int sl_ = (sidx) & 3; long ko_ = (long)(sidx) * 32; \
    gload16(Ag0 + ko_, &As[sl_][wave * 16][0]); \
    gload16(Ag1 + ko_, &As[sl_][64 + wave * 16][0]); \
    gload16(Bg0 + ko_, &Bs[sl_][wave * 16][0]); \
    gload16(Bg1 + ko_, &Bs[sl_][64 + wave * 16][0]); }

    STG(0) STG(1) STG(2)
    asm volatile("s_waitcnt vmcnt(8)" ::: "memory");
    GBAR()

    for (int s = 0; s < S; ++s) {
        const int sl = s & 3;
        if (s + 3 < S) STG(s + 3)
        bf16x8 a[4], b[4];
#pragma unroll
        for (int mt = 0; mt < 4; ++mt)
            a[mt] = *reinterpret_cast<const bf16x8*>(&As[sl][wm * 64 + mt * 16 + lr][gsw]);
#pragma unroll
        for (int nt = 0; nt < 4; ++nt)
            b[nt] = *reinterpret_cast<const bf16x8*>(&Bs[sl][wn * 64 + nt * 16 + lr][gsw]);
        __builtin_amdgcn_s_setprio(1);
#pragma unroll
        for (int mt = 0; mt < 4; ++mt)
#pragma unroll
            for (int nt = 0; nt < 4; ++nt)
                acc[mt][nt] = MFMA16(a[mt], b[nt], acc[mt][nt]);
        __builtin_amdgcn_s_setprio(0);
        RING_WAIT(s, S)
        GBAR()
    }
#undef STG
#pragma unroll
    for (int mt = 0; mt < 4; ++mt)
#pragma unroll
        for (int nt = 0; nt < 4; ++nt)
#pragma unroll
            for (int r = 0; r < 4; ++r) {
                int row = m0 + wm * 64 + mt * 16 + lg * 4 + r;
                int col = n0 + wn * 64 + nt * 16 + lr;
                float v = acc[mt][nt][r];
                if (EPI == 2) {
                    v += bias[col];
                    v = 0.5f * v * (1.f + erff(v * 0.70710678118f));
                }
                if (EPI == 0)
                    reinterpret_cast<float*>(Cout)[(long)row * ldc + col] = v;
                else
                    reinterpret_cast<unsigned short*>(Cout)[(long)row * ldc + col] = f2bu(v);
            }
}

// ---------------------------------------------------------------- fuse2: [8192,2048] x [2048,16] skinny GEMM
__global__ __launch_bounds__(256) void k_fuse2(const unsigned short* __restrict__ hid,
                                               const unsigned short* __restrict__ Wf2Tp,
                                               float* __restrict__ logits4) {
    const int mt = blockIdx.x, kq = blockIdx.y;
    const int tid = threadIdx.x, wave = tid >> 6, lane = tid & 63;
    const int lr = lane & 15, lg = lane >> 4;
    const int m0 = mt * 128 + wave * 32;
    const int kb = kq * 512;
    const unsigned short* a0p = hid + (long)(m0 + lr) * 2048 + kb + lg * 8;
    const unsigned short* a1p = a0p + (long)16 * 2048;
    const unsigned short* bp = Wf2Tp + (long)lr * 2048 + kb + lg * 8;
    f32x4 acc0 = {0, 0, 0, 0}, acc1 = {0, 0, 0, 0};
#pragma unroll 4
    for (int kk = 0; kk < 16; ++kk) {
        bf16x8 a0 = *reinterpret_cast<const bf16x8*>(a0p + kk * 32);
        bf16x8 a1 = *reinterpret_cast<const bf16x8*>(a1p + kk * 32);
        bf16x8 b = *reinterpret_cast<const bf16x8*>(bp + kk * 32);
        acc0 = MFMA16(a0, b, acc0);
        acc1 = MFMA16(a1, b, acc1);
    }
    float* out = logits4 + (long)kq * NTOK * 16;
#pragma unroll
    for (int r = 0; r < 4; ++r) {
        out[(long)(m0 + lg * 4 + r) * 16 + lr] = acc0[r];
        out[(long)(m0 + 16 + lg * 4 + r) * 16 + lr] = acc1[r];
    }
}

// ---------------------------------------------------------------- conv(k=4) + silu + per-head l2norm
__global__ __launch_bounds__(256) void k_conv_silu(const unsigned short* __restrict__ QKVp,
                                                   const float* __restrict__ cwq,
                                                   const float* __restrict__ cwk,
                                                   const float* __restrict__ cwv,
                                                   unsigned short* __restrict__ qn,
                                                   unsigned short* __restrict__ kn,
                                                   unsigned short* __restrict__ v_blc) {
    int tok = blockIdx.x;
    int b = tok >> 11, l = tok & 2047;
    int t = threadIdx.x;
    float y[12];
#pragma unroll
    for (int j = 0; j < 12; ++j) {
        int c = t + 256 * j;
        const float* cw = (j < 4) ? &cwq[c * 4] : (j < 8) ? &cwk[(c - 1024) * 4] : &cwv[(c - 2048) * 4];
        float s = 0.f;
#pragma unroll
        for (int jj = 0; jj < 4; ++jj) {
            int tl = l - 3 + jj;
            if (tl >= 0) s += bu2f(QKVp[((long)(b * L_ + tl)) * 3072 + c]) * cw[jj];
        }
        y[j] = s / (1.f + expf(-s));
    }
    float sq[8];
#pragma unroll
    for (int j = 0; j < 8; ++j) sq[j] = y[j] * y[j];
    int wave = t >> 6, lane = t & 63;
#pragma unroll
    for (int off = 32; off; off >>= 1)
#pragma unroll
        for (int j = 0; j < 8; ++j) sq[j] += __shfl_down(sq[j], off);
    __shared__ float red[4][8];
    if (lane == 0)
#pragma unroll
        for (int j = 0; j < 8; ++j) red[wave][j] = sq[j];
    __syncthreads();
    float tot[8];
#pragma unroll
    for (int j = 0; j < 8; ++j) tot[j] = red[0][j] + red[1][j] + red[2][j] + red[3][j];
#pragma unroll
    for (int h = 0; h < 4; ++h) {
        float sc = rsqrtf(tot[h] + 1e-6f);
        qn[((long)(b * H_ + h) * L_ + l) * 256 + t] = f2bu(y[h] * sc);
    }
#pragma unroll
    for (int h = 0; h < 4; ++h) {
        float sc = rsqrtf(tot[4 + h] + 1e-6f);
        kn[((long)(b * H_ + h) * L_ + l) * 256 + t] = f2bu(y[4 + h] * sc);
    }
#pragma unroll
    for (int h = 0; h < 4; ++h)
        v_blc[(long)tok * 1024 + h * 256 + t] = f2bu(y[8 + h]);
}

// ---------------------------------------------------------------- D1: per-(b,h,chunk) UT transform
__global__ __launch_bounds__(256) void k_delta_chunk(const unsigned short* __restrict__ qn,
                                                     const unsigned short* __restrict__ kn,
                                                     const unsigned short* __restrict__ v_blc,
                                                     const float* __restrict__ beta,
                                                     unsigned short* __restrict__ u_buf,
                                                     unsigned short* __restrict__ w_buf,
                                                     unsigned short* __restrict__ local_buf,
                                                     unsigned short* __restrict__ kT_buf) {
    int bid = blockIdx.x;          // bh*64 + n
    int n = bid & 63, bh = bid >> 6;
    int b = bh >> 2, h = bh & 3;
    int t0 = n * 32;
    __shared__ __align__(16) unsigned short k_s[32][264];
    __shared__ __align__(16) unsigned short vbT[256][40];
    __shared__ __align__(16) unsigned short kbT[256][40];
    __shared__ __align__(16) float att[32][33];
    __shared__ __align__(16) unsigned short att_b[32][40];
    __shared__ float bet[32];
    int tid = threadIdx.x, wave = tid >> 6, lane = tid & 63;
    int lr = lane & 15, lg = lane >> 4;

    // --- stage
    {
        int row = tid >> 3;
        int cc = (tid & 7) * 32;
        float brow = beta[(long)bh * L_ + t0 + row];
        if ((tid & 7) == 0) bet[row] = brow;
        const uint4* kp = reinterpret_cast<const uint4*>(&kn[((long)bh * L_ + t0 + row) * 256 + cc]);
        const uint4* vp = reinterpret_cast<const uint4*>(&v_blc[((long)(b * L_ + t0 + row)) * 1024 + h * 256 + cc]);
        unsigned short kv[32], vv[32];
#pragma unroll
        for (int g = 0; g < 4; ++g) {
            uint4 x = kp[g];
            *reinterpret_cast<uint4*>(&kv[g * 8]) = x;
            *reinterpret_cast<uint4*>(&k_s[row][cc + g * 8]) = x;
            *reinterpret_cast<uint4*>(&vv[g * 8]) = vp[g];
        }
#pragma unroll
        for (int e = 0; e < 32; ++e) {
            kbT[cc + e][row] = f2bu(bu2f(kv[e]) * brow);
            vbT[cc + e][row] = f2bu(bu2f(vv[e]) * brow);
        }
    }
    __syncthreads();

    // --- kT pack (coalesced global write)
    {
        unsigned short tmp[32];
#pragma unroll
        for (int t = 0; t < 32; ++t) tmp[t] = k_s[t][tid];
#pragma unroll
        for (int g = 0; g < 4; ++g)
            *reinterpret_cast<uint4*>(&kT_buf[((long)bid * 256 + tid) * 32 + g * 8]) =
                *reinterpret_cast<uint4*>(&tmp[g * 8]);
    }

    // --- S-phase: G = k k^T (scaled -beta[i]), S2 = q k^T (local)
    {
        int i0 = (wave & 1) * 16, j0 = (wave >> 1) * 16;
        f32x4 G = {0, 0, 0, 0}, S2 = {0, 0, 0, 0};
#pragma unroll
        for (int kk = 0; kk < 8; ++kk) {
            bf16x8 bk = *reinterpret_cast<const bf16x8*>(&k_s[j0 + lr][kk * 32 + lg * 8]);
            bf16x8 ak = *reinterpret_cast<const bf16x8*>(&k_s[i0 + lr][kk * 32 + lg * 8]);
            bf16x8 aq = *reinterpret_cast<const bf16x8*>(&qn[((long)bh * L_ + t0 + i0 + lr) * 256 + kk * 32 + lg * 8]);
            G = MFMA16(ak, bk, G);
            S2 = MFMA16(aq, bk, S2);
        }
#pragma unroll
        for (int r = 0; r < 4; ++r) {
            int i = i0 + lg * 4 + r, j = j0 + lr;
            att[i][j] = (j < i) ? -bet[i] * G[r] : 0.f;
            local_buf[(long)bid * 1024 + i * 32 + j] = f2bu((j <= i) ? S2[r] : 0.f);
        }
    }
    __syncthreads();

    // --- forward substitution: lanes 0..31 of wave 0 only (rule #18 fences)
    if (wave == 0) {
        for (int i = 1; i < 32; ++i) {
            float upd = 0.f;
            if (lane < i) {
                for (int j = lane + 1; j < i; ++j) upd += att[i][j] * att[j][lane];
            }
            asm volatile("s_waitcnt lgkmcnt(0)" ::: "memory");
            __builtin_amdgcn_sched_barrier(0);
            if (lane < i) att[i][lane] += upd;
            asm volatile("s_waitcnt lgkmcnt(0)" ::: "memory");
            __builtin_amdgcn_sched_barrier(0);
        }
    }
    __syncthreads();
    // att + I, to bf16
    for (int e = tid; e < 1024; e += 256) {
        int i = e >> 5, j = e & 31;
        att_b[i][j] = f2bu(att[i][j] + ((i == j) ? 1.f : 0.f));
    }
    __syncthreads();

    // --- u = att @ (v*beta), w = att @ (k*beta)
    {
        int mt = wave & 1;
        bf16x8 afr = *reinterpret_cast<const bf16x8*>(&att_b[mt * 16 + lr][lg * 8]);
        f32x4 z = {0, 0, 0, 0};
#pragma unroll
        for (int ntt = 0; ntt < 8; ++ntt) {
            int n0c = (wave >> 1) * 128 + ntt * 16;
            bf16x8 bu = *reinterpret_cast<const bf16x8*>(&vbT[n0c + lr][lg * 8]);
            bf16x8 bw = *reinterpret_cast<const bf16x8*>(&kbT[n0c + lr][lg * 8]);
            f32x4 ut = MFMA16(afr, bu, z);
            f32x4 wt = MFMA16(afr, bw, z);
#pragma unroll
            for (int r = 0; r < 4; ++r) {
                int t = mt * 16 + lg * 4 + r, c = n0c + lr;
                u_buf[((long)bid * 32 + t) * 256 + c] = f2bu(ut[r]);
                w_buf[((long)bid * 32 + t) * 256 + c] = f2bu(wt[r]);
            }
        }
    }
}

// ---------------------------------------------------------------- D2: sequential scan over chunks (v6)
// 256 blocks: bh = bid & 15 (XCD-local), dvb = bid >> 4 (dv-slice of 16).
// waves 0,1 = X=w@S path (token halves), waves 2,3 = O=q@S path.
// All per-chunk operands staged into a 2-slot LDS ring via global_load_lds
// one chunk ahead; single vmcnt(0) at chunk end.
__global__ __launch_bounds__(256, 1) void k_scan(const unsigned short* __restrict__ qn,
                                                 const unsigned short* __restrict__ u_buf,
                                                 const unsigned short* __restrict__ w_buf,
                                                 const unsigned short* __restrict__ local_buf,
                                                 const unsigned short* __restrict__ kT_buf,
                                                 unsigned short* __restrict__ gate_in) {
    int bid = blockIdx.x;
    int bh = bid & 15, dvb = bid >> 4;
    int b = bh >> 2, h = bh & 3;
    int dc0 = dvb * 16;
    __shared__ __align__(16) unsigned short Ws[2][32][256];   // 32 KB
    __shared__ __align__(16) unsigned short Qs[2][32][256];   // 32 KB
    __shared__ __align__(16) unsigned short KTs[2][256][32];  // 32 KB
    __shared__ __align__(16) unsigned short Us[2][32][16];    // 2 KB
    __shared__ __align__(16) unsigned short Ls[2][32][32];    // 4 KB
    __shared__ __align__(16) unsigned short Tb[16][264];      // state mirror
    __shared__ __align__(16) unsigned short uaT[16][40];
    const int tid = threadIdx.x, wave = tid >> 6, lane = tid & 63;
    const int lr = lane & 15, lg = lane >> 4;
    const int wi = wave & 1;        // token half
    const bool isW = wave < 2;      // X path vs O path
    const int c0w = wave * 64;      // state c-quadrant for update
    f32x4 Tacc[4] = {};
    for (int e = tid; e < 16 * 264; e += 256) (&Tb[0][0])[e] = 0;
    const unsigned short* q_bh = qn + (long)bh * L_ * 256;
    const unsigned short* u_bh = u_buf + (long)bh * 64 * 8192;
    const unsigned short* w_bh = w_buf + (long)bh * 64 * 8192;
    const unsigned short* l_bh = local_buf + (long)bh * 64 * 1024;
    const unsigned short* kT_bh = kT_buf + (long)bh * 64 * 8192;

    int wqrow[4], wqoff[4];
#pragma unroll
    for (int j = 0; j < 4; ++j) {
        int i = wave * 4 + j;
        int row = 2 * i + (lane >> 5);
        wqrow[j] = 2 * i;
        wqoff[j] = row * 256 + (((lane & 31) ^ (row & 7)) * 8);
    }
    int ktrow[4], ktoff[4];
#pragma unroll
    for (int j = 0; j < 4; ++j) {
        int i = wave * 4 + j;
        int row = i * 16 + (lane >> 2);
        ktrow[j] = i * 16;
        ktoff[j] = row * 32 + ((((lane & 3) ^ (row & 3)) ^ ((row >> 2) & 3)) * 8);
    }
    const int uoff = (lane >> 1) * 256 + dc0 + (lane & 1) * 8;
    const int lrow = (wave - 1) * 16;
    const int loff = (lrow + (lane >> 2)) * 32 + (lane & 3) * 8;

#define STAGE(sl_, n_) { \
    long o8_ = (long)(n_) * 8192; \
    _Pragma("unroll") for (int j = 0; j < 4; ++j) { \
        gload16(w_bh + o8_ + wqoff[j], &Ws[sl_][wqrow[j]][0]); \
        gload16(q_bh + o8_ + wqoff[j], &Qs[sl_][wqrow[j]][0]); \
        gload16(kT_bh + o8_ + ktoff[j], &KTs[sl_][ktrow[j]][0]); \
    } \
    if (wave == 0) gload16(u_bh + o8_ + uoff, &Us[sl_][0][0]); \
    if (wave == 1 || wave == 2) gload16(l_bh + (long)(n_) * 1024 + loff, &Ls[sl_][lrow][0]); }

    STAGE(0, 0)
    asm volatile("s_waitcnt vmcnt(0)" ::: "memory");
    __syncthreads();

    for (int n = 0; n < 64; ++n) {
        const int sl = n & 1;
        if (n + 1 < 64) STAGE(sl ^ 1, n + 1)
        const unsigned short* wq = isW ? &Ws[sl][0][0] : &Qs[sl][0][0];
        f32x4 P0 = {0, 0, 0, 0}, P1 = {0, 0, 0, 0}, P2 = {0, 0, 0, 0}, P3 = {0, 0, 0, 0};
#pragma unroll
        for (int kk = 0; kk < 2; ++kk) {
#pragma unroll
            for (int q4 = 0; q4 < 4; ++q4) {
                int kidx = kk * 4 + q4;
                bf16x8 a = *reinterpret_cast<const bf16x8*>(
                    wq + (16 * wi + lr) * 256 + (((kidx * 4 + lg) ^ (lr & 7)) * 8));
                bf16x8 t = *reinterpret_cast<const bf16x8*>(&Tb[lr][kidx * 32 + lg * 8]);
                if (q4 == 0) P0 = MFMA16(a, t, P0);
                else if (q4 == 1) P1 = MFMA16(a, t, P1);
                else if (q4 == 2) P2 = MFMA16(a, t, P2);
                else P3 = MFMA16(a, t, P3);
            }
        }
        f32x4 P;
#pragma unroll
        for (int r = 0; r < 4; ++r) P[r] = (P0[r] + P1[r]) + (P2[r] + P3[r]);
        if (isW) {
#pragma unroll
            for (int r = 0; r < 4; ++r) {
                float uv = bu2f(Us[sl][16 * wi + lg * 4 + r][lr]);
                uaT[lr][16 * wi + lg * 4 + r] = f2bu(uv - P[r]);
            }
        }
        RAWBAR()
        bf16x8 uaA = *reinterpret_cast<const bf16x8*>(&uaT[lr][lg * 8]);
        if (!isW) {
            bf16x8 lA = *reinterpret_cast<const bf16x8*>(&Ls[sl][16 * wi + lr][lg * 8]);
            f32x4 O = MFMA16(lA, uaA, P);
#pragma unroll
            for (int r = 0; r < 4; ++r) {
                long row = (long)b * L_ + n * 32 + 16 * wi + lg * 4 + r;
                gate_in[row * 4096 + 3072 + h * 256 + dc0 + lr] = f2bu(O[r]);
            }
        }
#pragma unroll
        for (int cc = 0; cc < 4; ++cc) {
            int rr = c0w + cc * 16 + lr;
            bf16x8 kB = *reinterpret_cast<const bf16x8*>(
                &KTs[sl][rr][(((lg ^ (rr & 3)) ^ ((rr >> 2) & 3)) * 8)]);
            Tacc[cc] = MFMA16(uaA, kB, Tacc[cc]);
        }
#pragma unroll
        for (int cc = 0; cc < 4; ++cc)
#pragma unroll
            for (int r = 0; r < 4; ++r)
                Tb[lg * 4 + r][c0w + cc * 16 + lr] = f2bu(Tacc[cc][r]);
        asm volatile("s_waitcnt vmcnt(0)" ::: "memory");
        RAWBAR()
    }
#undef STAGE
}

// ---------------------------------------------------------------- FIR depthwise convs (k=3 and k=31)
__global__ __launch_bounds__(256) void k_fir(const unsigned short* __restrict__ v_blc,
                                             const float* __restrict__ ws3,
                                             const float* __restrict__ wl31,
                                             unsigned short* __restrict__ gate_in) {
    __shared__ unsigned short xs[94][256];  // 64 + 30 halo
    int b = blockIdx.y, tt = blockIdx.x * 64, c0 = blockIdx.z * 256;
    int tid = threadIdx.x;
    for (int r = 0; r < 94; ++r) {
        int t = tt - 30 + r;
        xs[r][tid] = (t >= 0) ? v_blc[((long)(b * L_ + t)) * 1024 + c0 + tid] : (unsigned short)0;
    }
    int c = c0 + tid;
    float wl[31], ws[3];
#pragma unroll
    for (int j = 0; j < 31; ++j) wl[j] = wl31[(long)c * 31 + j];
#pragma unroll
    for (int j = 0; j < 3; ++j) ws[j] = ws3[(long)c * 3 + j];
    __syncthreads();
    for (int t = 0; t < 64; ++t) {
        float accl = 0.f, accs = 0.f;
#pragma unroll
        for (int j = 0; j < 31; ++j) accl += bu2f(xs[t + j][tid]) * wl[j];
#pragma unroll
        for (int j = 0; j < 3; ++j) accs += bu2f(xs[t + 28 + j][tid]) * ws[j];
        long row = (long)b * L_ + tt + t;
        gate_in[row * 4096 + 1024 + c] = f2bu(accs);
        gate_in[row * 4096 + 2048 + c] = f2bu(accl);
    }
}

// ---------------------------------------------------------------- gating + RMSNorm
__global__ __launch_bounds__(256) void k_gate(const float* __restrict__ logits4,
                                              const float* __restrict__ b_fuse2,
                                              const float* __restrict__ log_tau,
                                              const float* __restrict__ norm_w,
                                              const unsigned short* __restrict__ gate_in,
                                              const unsigned short* __restrict__ v_blc,
                                              unsigned short* __restrict__ o_norm) {
    int tok = blockIdx.x;
    int tid = threadIdx.x;
    __shared__ float lg_s[16];
    __shared__ float red[4][4];
    if (tid < 16) {
        long o = (long)tok * 16 + tid;
        lg_s[tid] = logits4[o] + logits4[(long)NTOK * 16 + o] +
                    logits4[(long)2 * NTOK * 16 + o] + logits4[(long)3 * NTOK * 16 + o] +
                    b_fuse2[tid];
    }
    __syncthreads();
    float o[4];
#pragma unroll
    for (int h = 0; h < 4; ++h) {
        float l0 = lg_s[h * 4 + 0], l1 = lg_s[h * 4 + 1], l2 = lg_s[h * 4 + 2], l3 = lg_s[h * 4 + 3];
        float praw = 1.f / (1.f + expf(-l3));
        float fl_ = 0.01f + 0.09f * (1.f - praw);
        float pval = (1.f - fl_) * praw;
        float itau = expf(-log_tau[h]);
        float a0 = l0 * itau, a1 = l1 * itau, a2 = l2 * itau;
        float m = fmaxf(a0, fmaxf(a1, a2));
        float e0 = expf(a0 - m), e1 = expf(a1 - m), e2 = expf(a2 - m);
        float inv = (1.f - pval) / (e0 + e1 + e2);
        long base = (long)tok * 4096;
        float fs = bu2f(gate_in[base + 1024 + h * 256 + tid]);
        float flv = bu2f(gate_in[base + 2048 + h * 256 + tid]);
        float dd = bu2f(gate_in[base + 3072 + h * 256 + tid]);
        float vv = bu2f(v_blc[(long)tok * 1024 + h * 256 + tid]);
        o[h] = e0 * inv * fs + e1 * inv * flv + e2 * inv * dd + pval * vv;
    }
    int wave = tid >> 6, lane = tid & 63;
    float s[4];
#pragma unroll
    for (int h = 0; h < 4; ++h) s[h] = o[h] * o[h];
#pragma unroll
    for (int off = 32; off; off >>= 1)
#pragma unroll
        for (int h = 0; h < 4; ++h) s[h] += __shfl_down(s[h], off);
    if (lane == 0)
#pragma unroll
        for (int h = 0; h < 4; ++h) red[wave][h] = s[h];
    __syncthreads();
#pragma unroll
    for (int h = 0; h < 4; ++h) {
        float tot = red[0][h] + red[1][h] + red[2][h] + red[3][h];
        float sc = rsqrtf(tot * (1.f / 256.f) + 1e-5f);
        o_norm[(long)tok * 1024 + h * 256 + tid] = f2bu(o[h] * sc * norm_w[tid]);
    }
}

// ----------------------------------------------------------------
extern "C" void kernel_launch(void* const* d_in, const int* in_sizes, int n_in,
                              void* d_out, int out_size, void* d_ws, size_t ws_size,
                              hipStream_t stream) {
    const float* hs = (const float*)d_in[0];
    const float* W_q = (const float*)d_in[1];
    const float* W_k = (const float*)d_in[2];
    const float* W_v = (const float*)d_in[3];
    const float* W_b = (const float*)d_in[4];
    const float* cwq = (const float*)d_in[5];
    const float* cwk = (const float*)d_in[6];
    const float* cwv = (const float*)d_in[7];
    const float* fir_s_w = (const float*)d_in[8];
    const float* fir_l_w = (const float*)d_in[9];
    const float* W_f1 = (const float*)d_in[10];
    const float* b_f1 = (const float*)d_in[11];
    const float* W_f2 = (const float*)d_in[12];
    const float* b_f2 = (const float*)d_in[13];
    const float* log_tau = (const float*)d_in[14];
    const float* norm_w = (const float*)d_in[15];
    const float* W_o = (const float*)d_in[16];

    char* ws = (char*)d_ws;
    size_t off = 0;
    auto alloc = [&](size_t bytes) { size_t o = off; off += (bytes + 255) & ~(size_t)255; return o; };
    unsigned short* gate_in = (unsigned short*)(ws + alloc((size_t)NTOK * 4096 * 2));
    unsigned short* QKVp    = (unsigned short*)(ws + alloc((size_t)NTOK * 3072 * 2));
    unsigned short* WqkvT   = (unsigned short*)(ws + alloc((size_t)3072 * 1024 * 2));
    unsigned short* Wf1T    = (unsigned short*)(ws + alloc((size_t)2048 * 4096 * 2));
    unsigned short* WoT     = (unsigned short*)(ws + alloc((size_t)1024 * 1024 * 2));
    unsigned short* Wf2Tp   = (unsigned short*)(ws + alloc((size_t)128 * 2048 * 2));
    float*          beta    = (float*)(ws + alloc((size_t)16 * 2048 * 4));
    unsigned short* qn      = (unsigned short*)(ws + alloc((size_t)16 * 2048 * 256 * 2));
    unsigned short* kn      = (unsigned short*)(ws + alloc((size_t)16 * 2048 * 256 * 2));
    unsigned short* v_blc   = (unsigned short*)(ws + alloc((size_t)NTOK * 1024 * 2));
    unsigned short* u_buf   = (unsigned short*)(ws + alloc((size_t)16 * 64 * 8192 * 2));
    unsigned short* w_buf   = (unsigned short*)(ws + alloc((size_t)16 * 64 * 8192 * 2));
    unsigned short* locb    = (unsigned short*)(ws + alloc((size_t)16 * 64 * 1024 * 2));
    unsigned short* kT_buf  = (unsigned short*)(ws + alloc((size_t)16 * 64 * 8192 * 2));
    float*          logits4 = (float*)(ws + alloc((size_t)4 * NTOK * 16 * 4));
    unsigned short* o_norm  = (unsigned short*)(ws + alloc((size_t)NTOK * 1024 * 2));
    unsigned short* hid     = QKVp;  // alias: QKVp dead after conv_silu

    // weight prep
    k_transpose<<<dim3(32, 32), 256, 0, stream>>>(W_q, WqkvT, 1024, 1024);
    k_transpose<<<dim3(32, 32), 256, 0, stream>>>(W_k, WqkvT + (size_t)1024 * 1024, 1024, 1024);
    k_transpose<<<dim3(32, 32), 256, 0, stream>>>(W_v, WqkvT + (size_t)2048 * 1024, 1024, 1024);
    k_transpose<<<dim3(64, 128), 256, 0, stream>>>(W_f1, Wf1T, 4096, 2048);
    k_transpose<<<dim3(32, 32), 256, 0, stream>>>(W_o, WoT, 1024, 1024);
    k_padT2<<<1024, 256, 0, stream>>>(W_f2, Wf2Tp);
    // activations prep (hs -> bf16 gate_in + fused beta)
    k_cvt_beta<<<8192, 256, 0, stream>>>((const float4*)hs, W_b, gate_in, beta);
    // QKV projection: M=8192 N=3072 K=1024, grid 24*64=1536 (%8==0)
    k_gemm<1><<<24 * 64, 256, 0, stream>>>(gate_in, 4096, WqkvT, 1024, QKVp, 3072, nullptr,
                                           1024, 24);
    k_conv_silu<<<8192, 256, 0, stream>>>(QKVp, cwq, cwk, cwv, qn, kn, v_blc);
    // delta rule
    k_delta_chunk<<<1024, 256, 0, stream>>>(qn, kn, v_blc, beta, u_buf, w_buf, locb, kT_buf);
    k_scan<<<256, 256, 0, stream>>>(qn, u_buf, w_buf, locb, kT_buf, gate_in);
    // FIR paths
    k_fir<<<dim3(32, 4, 4), 256, 0, stream>>>(v_blc, fir_s_w, fir_l_w, gate_in);
    // fusion MLP: M=8192 N=2048 K=4096, grid 16*64=1024
    k_gemm<2><<<16 * 64, 256, 0, stream>>>(gate_in, 4096, Wf1T, 4096, hid, 2048, b_f1,
                                           4096, 16);
    // fuse2: skinny K-split kernel, grid (64 m-tiles, 4 k-quarters)
    k_fuse2<<<dim3(64, 4), 256, 0, stream>>>(hid, Wf2Tp, logits4);
    k_gate<<<8192, 256, 0, stream>>>(logits4, b_f2, log_tau, norm_w, gate_in, v_blc, o_norm);
    // output projection: M=8192 N=1024 K=1024, grid 8*64=512
    k_gemm<0><<<8 * 64, 256, 0, stream>>>(o_norm, 1024, WoT, 1024, (float*)d_out, 1024, nullptr,
                                          1024, 8);
}

// Round 16
// 636.418 us; speedup vs baseline: 1.1129x; 1.1129x over previous
//
#include <hip/hip_runtime.h>
#include <hip/hip_bf16.h>

#define B_ 4
#define L_ 2048
#define D_ 1024
#define H_ 4
#define DK_ 256
#define DV_ 256
#define NCH 64
#define NTOK 8192

typedef __attribute__((ext_vector_type(8))) short bf16x8;
typedef __attribute__((ext_vector_type(4))) float f32x4;
typedef unsigned int u32;

__device__ __forceinline__ float bu2f(unsigned short u) {
    union { unsigned int i; float f; } x; x.i = ((unsigned int)u) << 16; return x.f;
}
__device__ __forceinline__ unsigned short f2bu(float f) {
    union { __hip_bfloat16 h; unsigned short u; } x; x.h = __float2bfloat16(f); return x.u;
}
#define MFMA16(a, b, c) __builtin_amdgcn_mfma_f32_16x16x32_bf16(a, b, c, 0, 0, 0)

__device__ __forceinline__ void gload16(const void* g, void* l) {
    __builtin_amdgcn_global_load_lds(
        (const __attribute__((address_space(1))) u32*)g,
        (__attribute__((address_space(3))) u32*)l, 16, 0, 0);
}

// Raw barrier: orders LDS (lgkmcnt only) + s_barrier; no vmcnt drain.
#define RAWBAR() { asm volatile("s_waitcnt lgkmcnt(0)" ::: "memory"); \
    __builtin_amdgcn_sched_barrier(0); \
    __builtin_amdgcn_s_barrier(); \
    __builtin_amdgcn_sched_barrier(0); }

// ---------------------------------------------------------------- transpose fp32 -> bf16, out[n][k] = in[k][n]
__global__ __launch_bounds__(256) void k_transpose(const float* __restrict__ in,
                                                   unsigned short* __restrict__ out,
                                                   int K, int N) {
    __shared__ float tile[32][33];
    int k0 = blockIdx.y * 32, n0 = blockIdx.x * 32;
    int tx = threadIdx.x & 31, ty = threadIdx.x >> 5;  // 32 x 8
#pragma unroll
    for (int r = 0; r < 4; ++r)
        tile[ty + 8 * r][tx] = in[(long)(k0 + ty + 8 * r) * N + n0 + tx];
    __syncthreads();
#pragma unroll
    for (int r = 0; r < 4; ++r)
        out[(long)(n0 + ty + 8 * r) * K + k0 + tx] = f2bu(tile[tx][ty + 8 * r]);
}

// W_fuse2 [2048][16] -> padded transpose [128][2048] bf16 (rows >=16 zero)
__global__ __launch_bounds__(256) void k_padT2(const float* __restrict__ W,
                                               unsigned short* __restrict__ out) {
    long idx = (long)blockIdx.x * 256 + threadIdx.x;  // 128*2048
    int n = (int)(idx >> 11), k = (int)(idx & 2047);
    out[idx] = (n < 16) ? f2bu(W[k * 16 + n]) : (unsigned short)0;
}

// hidden_states fp32 -> gate_in[:, 0:1024] bf16 (row stride 4096) + beta
__global__ __launch_bounds__(256) void k_cvt_beta(const float4* __restrict__ hs4,
                                                  const float* __restrict__ W_b,
                                                  unsigned short* __restrict__ gate_in,
                                                  float* __restrict__ beta) {
    int tok = blockIdx.x;
    int tid = threadIdx.x;
    float4 v = hs4[(long)tok * 256 + tid];
    ushort4 o;
    o.x = f2bu(v.x); o.y = f2bu(v.y); o.z = f2bu(v.z); o.w = f2bu(v.w);
    *reinterpret_cast<ushort4*>(&gate_in[(long)tok * 4096 + tid * 4]) = o;
    const float4* wb = reinterpret_cast<const float4*>(W_b);  // [1024] rows
    int c4 = tid * 4;
    float4 w0 = wb[c4], w1 = wb[c4 + 1], w2 = wb[c4 + 2], w3 = wb[c4 + 3];
    float s[4];
    s[0] = v.x * w0.x + v.y * w1.x + v.z * w2.x + v.w * w3.x;
    s[1] = v.x * w0.y + v.y * w1.y + v.z * w2.y + v.w * w3.y;
    s[2] = v.x * w0.z + v.y * w1.z + v.z * w2.z + v.w * w3.z;
    s[3] = v.x * w0.w + v.y * w1.w + v.z * w2.w + v.w * w3.w;
    int wave = tid >> 6, lane = tid & 63;
#pragma unroll
    for (int off = 32; off; off >>= 1)
#pragma unroll
        for (int h = 0; h < 4; ++h) s[h] += __shfl_down(s[h], off);
    __shared__ float red[4][4];
    if (lane == 0)
#pragma unroll
        for (int h = 0; h < 4; ++h) red[wave][h] = s[h];
    __syncthreads();
    if (tid < 4) {
        int h = tid;
        float tot = red[0][h] + red[1][h] + red[2][h] + red[3][h];
        int b = tok >> 11, l = tok & 2047;
        beta[((long)(b * H_ + h)) * L_ + l] = 1.f / (1.f + expf(-tot));
    }
}

// ---------------------------------------------------------------- main GEMM: C = A[M,K] * BT[N,K]^T
// m97 structure + T2 swizzle + __launch_bounds__(256,4).
// EPI: 0 = fp32 out, 1 = bf16 out, 2 = bf16 out with bias+gelu(exact)
template <int EPI>
__global__ __launch_bounds__(256, 4) void k_gemm(const unsigned short* __restrict__ A, int lda,
                                                 const unsigned short* __restrict__ BT, int ldb,
                                                 void* __restrict__ Cout, int ldc,
                                                 const float* __restrict__ bias,
                                                 int K, int gx) {
    __shared__ __align__(16) unsigned short As[128][64];
    __shared__ __align__(16) unsigned short Bs[128][64];
    const int tid = threadIdx.x;
    const int wave = tid >> 6, lane = tid & 63;
    const int wm = wave & 1, wn = wave >> 1;
    const int lr = lane & 15, lg = lane >> 4;
    const int nwg = gridDim.x;
    const int cpx = nwg >> 3;
    const int orig = blockIdx.x;
    const int wg = (orig & 7) * cpx + (orig >> 3);
    const int m0 = (wg / gx) * 128, n0 = (wg % gx) * 128;
    const int srow = wave * 32 + (lane >> 3);
    const int scol = (((lane & 7) ^ ((lane >> 3) & 7))) * 8;
    const unsigned short* Ap = &A[(long)(m0 + srow) * lda + scol];
    const unsigned short* Bp = &BT[(long)(n0 + srow) * ldb + scol];
    unsigned short* AsB = &As[wave * 32][0];
    unsigned short* BsB = &Bs[wave * 32][0];
    const unsigned short* AsF = &As[0][0];
    const unsigned short* BsF = &Bs[0][0];
    f32x4 acc[4][4] = {};
    for (int k0 = 0; k0 < K; k0 += 64) {
#pragma unroll
        for (int g = 0; g < 4; ++g) {
            gload16(Ap + (long)g * 8 * lda + k0, AsB + g * 8 * 64);
            gload16(Bp + (long)g * 8 * ldb + k0, BsB + g * 8 * 64);
        }
        __syncthreads();
#pragma unroll
        for (int ks = 0; ks < 2; ++ks) {
            bf16x8 af[4], bfr[4];
#pragma unroll
            for (int mt = 0; mt < 4; ++mt) {
                int r = wm * 64 + mt * 16 + lr;
                af[mt] = *reinterpret_cast<const bf16x8*>(
                    AsF + r * 64 + (((ks * 4 + lg) ^ (lr & 7)) * 8));
            }
#pragma unroll
            for (int nt = 0; nt < 4; ++nt) {
                int r = wn * 64 + nt * 16 + lr;
                bfr[nt] = *reinterpret_cast<const bf16x8*>(
                    BsF + r * 64 + (((ks * 4 + lg) ^ (lr & 7)) * 8));
            }
#pragma unroll
            for (int mt = 0; mt < 4; ++mt)
#pragma unroll
                for (int nt = 0; nt < 4; ++nt)
                    acc[mt][nt] = MFMA16(af[mt], bfr[nt], acc[mt][nt]);
        }
        __syncthreads();
    }
#pragma unroll
    for (int mt = 0; mt < 4; ++mt)
#pragma unroll
        for (int nt = 0; nt < 4; ++nt)
#pragma unroll
            for (int r = 0; r < 4; ++r) {
                int row = m0 + wm * 64 + mt * 16 + lg * 4 + r;
                int col = n0 + wn * 64 + nt * 16 + lr;
                float v = acc[mt][nt][r];
                if (EPI == 2) {
                    v += bias[col];
                    v = 0.5f * v * (1.f + erff(v * 0.70710678118f));
                }
                if (EPI == 0)
                    reinterpret_cast<float*>(Cout)[(long)row * ldc + col] = v;
                else
                    reinterpret_cast<unsigned short*>(Cout)[(long)row * ldc + col] = f2bu(v);
            }
}

// ---------------------------------------------------------------- fuse2: [8192,2048] x [2048,16] skinny GEMM
__global__ __launch_bounds__(256) void k_fuse2(const unsigned short* __restrict__ hid,
                                               const unsigned short* __restrict__ Wf2Tp,
                                               float* __restrict__ logits4) {
    const int mt = blockIdx.x, kq = blockIdx.y;
    const int tid = threadIdx.x, wave = tid >> 6, lane = tid & 63;
    const int lr = lane & 15, lg = lane >> 4;
    const int m0 = mt * 128 + wave * 32;
    const int kb = kq * 512;
    const unsigned short* a0p = hid + (long)(m0 + lr) * 2048 + kb + lg * 8;
    const unsigned short* a1p = a0p + (long)16 * 2048;
    const unsigned short* bp = Wf2Tp + (long)lr * 2048 + kb + lg * 8;
    f32x4 acc0 = {0, 0, 0, 0}, acc1 = {0, 0, 0, 0};
#pragma unroll 4
    for (int kk = 0; kk < 16; ++kk) {
        bf16x8 a0 = *reinterpret_cast<const bf16x8*>(a0p + kk * 32);
        bf16x8 a1 = *reinterpret_cast<const bf16x8*>(a1p + kk * 32);
        bf16x8 b = *reinterpret_cast<const bf16x8*>(bp + kk * 32);
        acc0 = MFMA16(a0, b, acc0);
        acc1 = MFMA16(a1, b, acc1);
    }
    float* out = logits4 + (long)kq * NTOK * 16;
#pragma unroll
    for (int r = 0; r < 4; ++r) {
        out[(long)(m0 + lg * 4 + r) * 16 + lr] = acc0[r];
        out[(long)(m0 + 16 + lg * 4 + r) * 16 + lr] = acc1[r];
    }
}

// ---------------------------------------------------------------- conv(k=4) + silu + per-head l2norm
__global__ __launch_bounds__(256) void k_conv_silu(const unsigned short* __restrict__ QKVp,
                                                   const float* __restrict__ cwq,
                                                   const float* __restrict__ cwk,
                                                   const float* __restrict__ cwv,
                                                   unsigned short* __restrict__ qn,
                                                   unsigned short* __restrict__ kn,
                                                   unsigned short* __restrict__ v_blc) {
    int tok = blockIdx.x;
    int b = tok >> 11, l = tok & 2047;
    int t = threadIdx.x;
    float y[12];
#pragma unroll
    for (int j = 0; j < 12; ++j) {
        int c = t + 256 * j;
        const float* cw = (j < 4) ? &cwq[c * 4] : (j < 8) ? &cwk[(c - 1024) * 4] : &cwv[(c - 2048) * 4];
        float s = 0.f;
#pragma unroll
        for (int jj = 0; jj < 4; ++jj) {
            int tl = l - 3 + jj;
            if (tl >= 0) s += bu2f(QKVp[((long)(b * L_ + tl)) * 3072 + c]) * cw[jj];
        }
        y[j] = s / (1.f + expf(-s));
    }
    float sq[8];
#pragma unroll
    for (int j = 0; j < 8; ++j) sq[j] = y[j] * y[j];
    int wave = t >> 6, lane = t & 63;
#pragma unroll
    for (int off = 32; off; off >>= 1)
#pragma unroll
        for (int j = 0; j < 8; ++j) sq[j] += __shfl_down(sq[j], off);
    __shared__ float red[4][8];
    if (lane == 0)
#pragma unroll
        for (int j = 0; j < 8; ++j) red[wave][j] = sq[j];
    __syncthreads();
    float tot[8];
#pragma unroll
    for (int j = 0; j < 8; ++j) tot[j] = red[0][j] + red[1][j] + red[2][j] + red[3][j];
#pragma unroll
    for (int h = 0; h < 4; ++h) {
        float sc = rsqrtf(tot[h] + 1e-6f);
        qn[((long)(b * H_ + h) * L_ + l) * 256 + t] = f2bu(y[h] * sc);
    }
#pragma unroll
    for (int h = 0; h < 4; ++h) {
        float sc = rsqrtf(tot[4 + h] + 1e-6f);
        kn[((long)(b * H_ + h) * L_ + l) * 256 + t] = f2bu(y[4 + h] * sc);
    }
#pragma unroll
    for (int h = 0; h < 4; ++h)
        v_blc[(long)tok * 1024 + h * 256 + t] = f2bu(y[8 + h]);
}

// ---------------------------------------------------------------- D1: per-(b,h,chunk) UT transform
__global__ __launch_bounds__(256) void k_delta_chunk(const unsigned short* __restrict__ qn,
                                                     const unsigned short* __restrict__ kn,
                                                     const unsigned short* __restrict__ v_blc,
                                                     const float* __restrict__ beta,
                                                     unsigned short* __restrict__ u_buf,
                                                     unsigned short* __restrict__ w_buf,
                                                     unsigned short* __restrict__ local_buf,
                                                     unsigned short* __restrict__ kT_buf) {
    int bid = blockIdx.x;          // bh*64 + n
    int n = bid & 63, bh = bid >> 6;
    int b = bh >> 2, h = bh & 3;
    int t0 = n * 32;
    __shared__ __align__(16) unsigned short k_s[32][264];
    __shared__ __align__(16) unsigned short vbT[256][40];
    __shared__ __align__(16) unsigned short kbT[256][40];
    __shared__ __align__(16) float att[32][33];
    __shared__ __align__(16) unsigned short att_b[32][40];
    __shared__ float bet[32];
    int tid = threadIdx.x, wave = tid >> 6, lane = tid & 63;
    int lr = lane & 15, lg = lane >> 4;

    // --- stage
    {
        int row = tid >> 3;
        int cc = (tid & 7) * 32;
        float brow = beta[(long)bh * L_ + t0 + row];
        if ((tid & 7) == 0) bet[row] = brow;
        const uint4* kp = reinterpret_cast<const uint4*>(&kn[((long)bh * L_ + t0 + row) * 256 + cc]);
        const uint4* vp = reinterpret_cast<const uint4*>(&v_blc[((long)(b * L_ + t0 + row)) * 1024 + h * 256 + cc]);
        unsigned short kv[32], vv[32];
#pragma unroll
        for (int g = 0; g < 4; ++g) {
            uint4 x = kp[g];
            *reinterpret_cast<uint4*>(&kv[g * 8]) = x;
            *reinterpret_cast<uint4*>(&k_s[row][cc + g * 8]) = x;
            *reinterpret_cast<uint4*>(&vv[g * 8]) = vp[g];
        }
#pragma unroll
        for (int e = 0; e < 32; ++e) {
            kbT[cc + e][row] = f2bu(bu2f(kv[e]) * brow);
            vbT[cc + e][row] = f2bu(bu2f(vv[e]) * brow);
        }
    }
    __syncthreads();

    // --- kT pack (coalesced global write)
    {
        unsigned short tmp[32];
#pragma unroll
        for (int t = 0; t < 32; ++t) tmp[t] = k_s[t][tid];
#pragma unroll
        for (int g = 0; g < 4; ++g)
            *reinterpret_cast<uint4*>(&kT_buf[((long)bid * 256 + tid) * 32 + g * 8]) =
                *reinterpret_cast<uint4*>(&tmp[g * 8]);
    }

    // --- S-phase: G = k k^T (scaled -beta[i]), S2 = q k^T (local)
    {
        int i0 = (wave & 1) * 16, j0 = (wave >> 1) * 16;
        f32x4 G = {0, 0, 0, 0}, S2 = {0, 0, 0, 0};
#pragma unroll
        for (int kk = 0; kk < 8; ++kk) {
            bf16x8 bk = *reinterpret_cast<const bf16x8*>(&k_s[j0 + lr][kk * 32 + lg * 8]);
            bf16x8 ak = *reinterpret_cast<const bf16x8*>(&k_s[i0 + lr][kk * 32 + lg * 8]);
            bf16x8 aq = *reinterpret_cast<const bf16x8*>(&qn[((long)bh * L_ + t0 + i0 + lr) * 256 + kk * 32 + lg * 8]);
            G = MFMA16(ak, bk, G);
            S2 = MFMA16(aq, bk, S2);
        }
#pragma unroll
        for (int r = 0; r < 4; ++r) {
            int i = i0 + lg * 4 + r, j = j0 + lr;
            att[i][j] = (j < i) ? -bet[i] * G[r] : 0.f;
            local_buf[(long)bid * 1024 + i * 32 + j] = f2bu((j <= i) ? S2[r] : 0.f);
        }
    }
    __syncthreads();

    // --- forward substitution: lanes 0..31 of wave 0 only (rule #18 fences)
    if (wave == 0) {
        for (int i = 1; i < 32; ++i) {
            float upd = 0.f;
            if (lane < i) {
                for (int j = lane + 1; j < i; ++j) upd += att[i][j] * att[j][lane];
            }
            asm volatile("s_waitcnt lgkmcnt(0)" ::: "memory");
            __builtin_amdgcn_sched_barrier(0);
            if (lane < i) att[i][lane] += upd;
            asm volatile("s_waitcnt lgkmcnt(0)" ::: "memory");
            __builtin_amdgcn_sched_barrier(0);
        }
    }
    __syncthreads();
    // att + I, to bf16
    for (int e = tid; e < 1024; e += 256) {
        int i = e >> 5, j = e & 31;
        att_b[i][j] = f2bu(att[i][j] + ((i == j) ? 1.f : 0.f));
    }
    __syncthreads();

    // --- u = att @ (v*beta), w = att @ (k*beta)
    {
        int mt = wave & 1;
        bf16x8 afr = *reinterpret_cast<const bf16x8*>(&att_b[mt * 16 + lr][lg * 8]);
        f32x4 z = {0, 0, 0, 0};
#pragma unroll
        for (int ntt = 0; ntt < 8; ++ntt) {
            int n0c = (wave >> 1) * 128 + ntt * 16;
            bf16x8 bu = *reinterpret_cast<const bf16x8*>(&vbT[n0c + lr][lg * 8]);
            bf16x8 bw = *reinterpret_cast<const bf16x8*>(&kbT[n0c + lr][lg * 8]);
            f32x4 ut = MFMA16(afr, bu, z);
            f32x4 wt = MFMA16(afr, bw, z);
#pragma unroll
            for (int r = 0; r < 4; ++r) {
                int t = mt * 16 + lg * 4 + r, c = n0c + lr;
                u_buf[((long)bid * 32 + t) * 256 + c] = f2bu(ut[r]);
                w_buf[((long)bid * 32 + t) * 256 + c] = f2bu(wt[r]);
            }
        }
    }
}

// ---------------------------------------------------------------- D2: sequential scan over chunks (v6)
// 256 blocks: bh = bid & 15 (XCD-local), dvb = bid >> 4 (dv-slice of 16).
// waves 0,1 = X=w@S path (token halves), waves 2,3 = O=q@S path.
// All per-chunk operands staged into a 2-slot LDS ring via global_load_lds
// one chunk ahead; single vmcnt(0) at chunk end.
__global__ __launch_bounds__(256, 1) void k_scan(const unsigned short* __restrict__ qn,
                                                 const unsigned short* __restrict__ u_buf,
                                                 const unsigned short* __restrict__ w_buf,
                                                 const unsigned short* __restrict__ local_buf,
                                                 const unsigned short* __restrict__ kT_buf,
                                                 unsigned short* __restrict__ gate_in) {
    int bid = blockIdx.x;
    int bh = bid & 15, dvb = bid >> 4;
    int b = bh >> 2, h = bh & 3;
    int dc0 = dvb * 16;
    __shared__ __align__(16) unsigned short Ws[2][32][256];   // 32 KB
    __shared__ __align__(16) unsigned short Qs[2][32][256];   // 32 KB
    __shared__ __align__(16) unsigned short KTs[2][256][32];  // 32 KB
    __shared__ __align__(16) unsigned short Us[2][32][16];    // 2 KB
    __shared__ __align__(16) unsigned short Ls[2][32][32];    // 4 KB
    __shared__ __align__(16) unsigned short Tb[16][264];      // state mirror
    __shared__ __align__(16) unsigned short uaT[16][40];
    const int tid = threadIdx.x, wave = tid >> 6, lane = tid & 63;
    const int lr = lane & 15, lg = lane >> 4;
    const int wi = wave & 1;        // token half
    const bool isW = wave < 2;      // X path vs O path
    const int c0w = wave * 64;      // state c-quadrant for update
    f32x4 Tacc[4] = {};
    for (int e = tid; e < 16 * 264; e += 256) (&Tb[0][0])[e] = 0;
    const unsigned short* q_bh = qn + (long)bh * L_ * 256;
    const unsigned short* u_bh = u_buf + (long)bh * 64 * 8192;
    const unsigned short* w_bh = w_buf + (long)bh * 64 * 8192;
    const unsigned short* l_bh = local_buf + (long)bh * 64 * 1024;
    const unsigned short* kT_bh = kT_buf + (long)bh * 64 * 8192;

    int wqrow[4], wqoff[4];
#pragma unroll
    for (int j = 0; j < 4; ++j) {
        int i = wave * 4 + j;
        int row = 2 * i + (lane >> 5);
        wqrow[j] = 2 * i;
        wqoff[j] = row * 256 + (((lane & 31) ^ (row & 7)) * 8);
    }
    int ktrow[4], ktoff[4];
#pragma unroll
    for (int j = 0; j < 4; ++j) {
        int i = wave * 4 + j;
        int row = i * 16 + (lane >> 2);
        ktrow[j] = i * 16;
        ktoff[j] = row * 32 + ((((lane & 3) ^ (row & 3)) ^ ((row >> 2) & 3)) * 8);
    }
    const int uoff = (lane >> 1) * 256 + dc0 + (lane & 1) * 8;
    const int lrow = (wave - 1) * 16;
    const int loff = (lrow + (lane >> 2)) * 32 + (lane & 3) * 8;

#define STAGE(sl_, n_) { \
    long o8_ = (long)(n_) * 8192; \
    _Pragma("unroll") for (int j = 0; j < 4; ++j) { \
        gload16(w_bh + o8_ + wqoff[j], &Ws[sl_][wqrow[j]][0]); \
        gload16(q_bh + o8_ + wqoff[j], &Qs[sl_][wqrow[j]][0]); \
        gload16(kT_bh + o8_ + ktoff[j], &KTs[sl_][ktrow[j]][0]); \
    } \
    if (wave == 0) gload16(u_bh + o8_ + uoff, &Us[sl_][0][0]); \
    if (wave == 1 || wave == 2) gload16(l_bh + (long)(n_) * 1024 + loff, &Ls[sl_][lrow][0]); }

    STAGE(0, 0)
    asm volatile("s_waitcnt vmcnt(0)" ::: "memory");
    __syncthreads();

    for (int n = 0; n < 64; ++n) {
        const int sl = n & 1;
        if (n + 1 < 64) STAGE(sl ^ 1, n + 1)
        const unsigned short* wq = isW ? &Ws[sl][0][0] : &Qs[sl][0][0];
        f32x4 P0 = {0, 0, 0, 0}, P1 = {0, 0, 0, 0}, P2 = {0, 0, 0, 0}, P3 = {0, 0, 0, 0};
#pragma unroll
        for (int kk = 0; kk < 2; ++kk) {
#pragma unroll
            for (int q4 = 0; q4 < 4; ++q4) {
                int kidx = kk * 4 + q4;
                bf16x8 a = *reinterpret_cast<const bf16x8*>(
                    wq + (16 * wi + lr) * 256 + (((kidx * 4 + lg) ^ (lr & 7)) * 8));
                bf16x8 t = *reinterpret_cast<const bf16x8*>(&Tb[lr][kidx * 32 + lg * 8]);
                if (q4 == 0) P0 = MFMA16(a, t, P0);
                else if (q4 == 1) P1 = MFMA16(a, t, P1);
                else if (q4 == 2) P2 = MFMA16(a, t, P2);
                else P3 = MFMA16(a, t, P3);
            }
        }
        f32x4 P;
#pragma unroll
        for (int r = 0; r < 4; ++r) P[r] = (P0[r] + P1[r]) + (P2[r] + P3[r]);
        if (isW) {
#pragma unroll
            for (int r = 0; r < 4; ++r) {
                float uv = bu2f(Us[sl][16 * wi + lg * 4 + r][lr]);
                uaT[lr][16 * wi + lg * 4 + r] = f2bu(uv - P[r]);
            }
        }
        RAWBAR()
        bf16x8 uaA = *reinterpret_cast<const bf16x8*>(&uaT[lr][lg * 8]);
        if (!isW) {
            bf16x8 lA = *reinterpret_cast<const bf16x8*>(&Ls[sl][16 * wi + lr][lg * 8]);
            f32x4 O = MFMA16(lA, uaA, P);
#pragma unroll
            for (int r = 0; r < 4; ++r) {
                long row = (long)b * L_ + n * 32 + 16 * wi + lg * 4 + r;
                gate_in[row * 4096 + 3072 + h * 256 + dc0 + lr] = f2bu(O[r]);
            }
        }
#pragma unroll
        for (int cc = 0; cc < 4; ++cc) {
            int rr = c0w + cc * 16 + lr;
            bf16x8 kB = *reinterpret_cast<const bf16x8*>(
                &KTs[sl][rr][(((lg ^ (rr & 3)) ^ ((rr >> 2) & 3)) * 8)]);
            Tacc[cc] = MFMA16(uaA, kB, Tacc[cc]);
        }
#pragma unroll
        for (int cc = 0; cc < 4; ++cc)
#pragma unroll
            for (int r = 0; r < 4; ++r)
                Tb[lg * 4 + r][c0w + cc * 16 + lr] = f2bu(Tacc[cc][r]);
        asm volatile("s_waitcnt vmcnt(0)" ::: "memory");
        RAWBAR()
    }
#undef STAGE
}

// ---------------------------------------------------------------- FIR depthwise convs (k=3 and k=31)
__global__ __launch_bounds__(256) void k_fir(const unsigned short* __restrict__ v_blc,
                                             const float* __restrict__ ws3,
                                             const float* __restrict__ wl31,
                                             unsigned short* __restrict__ gate_in) {
    __shared__ unsigned short xs[94][256];  // 64 + 30 halo
    int b = blockIdx.y, tt = blockIdx.x * 64, c0 = blockIdx.z * 256;
    int tid = threadIdx.x;
    for (int r = 0; r < 94; ++r) {
        int t = tt - 30 + r;
        xs[r][tid] = (t >= 0) ? v_blc[((long)(b * L_ + t)) * 1024 + c0 + tid] : (unsigned short)0;
    }
    int c = c0 + tid;
    float wl[31], ws[3];
#pragma unroll
    for (int j = 0; j < 31; ++j) wl[j] = wl31[(long)c * 31 + j];
#pragma unroll
    for (int j = 0; j < 3; ++j) ws[j] = ws3[(long)c * 3 + j];
    __syncthreads();
    for (int t = 0; t < 64; ++t) {
        float accl = 0.f, accs = 0.f;
#pragma unroll
        for (int j = 0; j < 31; ++j) accl += bu2f(xs[t + j][tid]) * wl[j];
#pragma unroll
        for (int j = 0; j < 3; ++j) accs += bu2f(xs[t + 28 + j][tid]) * ws[j];
        long row = (long)b * L_ + tt + t;
        gate_in[row * 4096 + 1024 + c] = f2bu(accs);
        gate_in[row * 4096 + 2048 + c] = f2bu(accl);
    }
}

// ---------------------------------------------------------------- gating + RMSNorm
__global__ __launch_bounds__(256) void k_gate(const float* __restrict__ logits4,
                                              const float* __restrict__ b_fuse2,
                                              const float* __restrict__ log_tau,
                                              const float* __restrict__ norm_w,
                                              const unsigned short* __restrict__ gate_in,
                                              const unsigned short* __restrict__ v_blc,
                                              unsigned short* __restrict__ o_norm) {
    int tok = blockIdx.x;
    int tid = threadIdx.x;
    __shared__ float lg_s[16];
    __shared__ float red[4][4];
    if (tid < 16) {
        long o = (long)tok * 16 + tid;
        lg_s[tid] = logits4[o] + logits4[(long)NTOK * 16 + o] +
                    logits4[(long)2 * NTOK * 16 + o] + logits4[(long)3 * NTOK * 16 + o] +
                    b_fuse2[tid];
    }
    __syncthreads();
    float o[4];
#pragma unroll
    for (int h = 0; h < 4; ++h) {
        float l0 = lg_s[h * 4 + 0], l1 = lg_s[h * 4 + 1], l2 = lg_s[h * 4 + 2], l3 = lg_s[h * 4 + 3];
        float praw = 1.f / (1.f + expf(-l3));
        float fl_ = 0.01f + 0.09f * (1.f - praw);
        float pval = (1.f - fl_) * praw;
        float itau = expf(-log_tau[h]);
        float a0 = l0 * itau, a1 = l1 * itau, a2 = l2 * itau;
        float m = fmaxf(a0, fmaxf(a1, a2));
        float e0 = expf(a0 - m), e1 = expf(a1 - m), e2 = expf(a2 - m);
        float inv = (1.f - pval) / (e0 + e1 + e2);
        long base = (long)tok * 4096;
        float fs = bu2f(gate_in[base + 1024 + h * 256 + tid]);
        float flv = bu2f(gate_in[base + 2048 + h * 256 + tid]);
        float dd = bu2f(gate_in[base + 3072 + h * 256 + tid]);
        float vv = bu2f(v_blc[(long)tok * 1024 + h * 256 + tid]);
        o[h] = e0 * inv * fs + e1 * inv * flv + e2 * inv * dd + pval * vv;
    }
    int wave = tid >> 6, lane = tid & 63;
    float s[4];
#pragma unroll
    for (int h = 0; h < 4; ++h) s[h] = o[h] * o[h];
#pragma unroll
    for (int off = 32; off; off >>= 1)
#pragma unroll
        for (int h = 0; h < 4; ++h) s[h] += __shfl_down(s[h], off);
    if (lane == 0)
#pragma unroll
        for (int h = 0; h < 4; ++h) red[wave][h] = s[h];
    __syncthreads();
#pragma unroll
    for (int h = 0; h < 4; ++h) {
        float tot = red[0][h] + red[1][h] + red[2][h] + red[3][h];
        float sc = rsqrtf(tot * (1.f / 256.f) + 1e-5f);
        o_norm[(long)tok * 1024 + h * 256 + tid] = f2bu(o[h] * sc * norm_w[tid]);
    }
}

// ----------------------------------------------------------------
extern "C" void kernel_launch(void* const* d_in, const int* in_sizes, int n_in,
                              void* d_out, int out_size, void* d_ws, size_t ws_size,
                              hipStream_t stream) {
    const float* hs = (const float*)d_in[0];
    const float* W_q = (const float*)d_in[1];
    const float* W_k = (const float*)d_in[2];
    const float* W_v = (const float*)d_in[3];
    const float* W_b = (const float*)d_in[4];
    const float* cwq = (const float*)d_in[5];
    const float* cwk = (const float*)d_in[6];
    const float* cwv = (const float*)d_in[7];
    const float* fir_s_w = (const float*)d_in[8];
    const float* fir_l_w = (const float*)d_in[9];
    const float* W_f1 = (const float*)d_in[10];
    const float* b_f1 = (const float*)d_in[11];
    const float* W_f2 = (const float*)d_in[12];
    const float* b_f2 = (const float*)d_in[13];
    const float* log_tau = (const float*)d_in[14];
    const float* norm_w = (const float*)d_in[15];
    const float* W_o = (const float*)d_in[16];

    char* ws = (char*)d_ws;
    size_t off = 0;
    auto alloc = [&](size_t bytes) { size_t o = off; off += (bytes + 255) & ~(size_t)255; return o; };
    unsigned short* gate_in = (unsigned short*)(ws + alloc((size_t)NTOK * 4096 * 2));
    unsigned short* QKVp    = (unsigned short*)(ws + alloc((size_t)NTOK * 3072 * 2));
    unsigned short* WqkvT   = (unsigned short*)(ws + alloc((size_t)3072 * 1024 * 2));
    unsigned short* Wf1T    = (unsigned short*)(ws + alloc((size_t)2048 * 4096 * 2));
    unsigned short* WoT     = (unsigned short*)(ws + alloc((size_t)1024 * 1024 * 2));
    unsigned short* Wf2Tp   = (unsigned short*)(ws + alloc((size_t)128 * 2048 * 2));
    float*          beta    = (float*)(ws + alloc((size_t)16 * 2048 * 4));
    unsigned short* qn      = (unsigned short*)(ws + alloc((size_t)16 * 2048 * 256 * 2));
    unsigned short* kn      = (unsigned short*)(ws + alloc((size_t)16 * 2048 * 256 * 2));
    unsigned short* v_blc   = (unsigned short*)(ws + alloc((size_t)NTOK * 1024 * 2));
    unsigned short* u_buf   = (unsigned short*)(ws + alloc((size_t)16 * 64 * 8192 * 2));
    unsigned short* w_buf   = (unsigned short*)(ws + alloc((size_t)16 * 64 * 8192 * 2));
    unsigned short* locb    = (unsigned short*)(ws + alloc((size_t)16 * 64 * 1024 * 2));
    unsigned short* kT_buf  = (unsigned short*)(ws + alloc((size_t)16 * 64 * 8192 * 2));
    float*          logits4 = (float*)(ws + alloc((size_t)4 * NTOK * 16 * 4));
    unsigned short* o_norm  = (unsigned short*)(ws + alloc((size_t)NTOK * 1024 * 2));
    unsigned short* hid     = QKVp;  // alias: QKVp dead after conv_silu

    // weight prep
    k_transpose<<<dim3(32, 32), 256, 0, stream>>>(W_q, WqkvT, 1024, 1024);
    k_transpose<<<dim3(32, 32), 256, 0, stream>>>(W_k, WqkvT + (size_t)1024 * 1024, 1024, 1024);
    k_transpose<<<dim3(32, 32), 256, 0, stream>>>(W_v, WqkvT + (size_t)2048 * 1024, 1024, 1024);
    k_transpose<<<dim3(64, 128), 256, 0, stream>>>(W_f1, Wf1T, 4096, 2048);
    k_transpose<<<dim3(32, 32), 256, 0, stream>>>(W_o, WoT, 1024, 1024);
    k_padT2<<<1024, 256, 0, stream>>>(W_f2, Wf2Tp);
    // activations prep (hs -> bf16 gate_in + fused beta)
    k_cvt_beta<<<8192, 256, 0, stream>>>((const float4*)hs, W_b, gate_in, beta);
    // QKV projection: M=8192 N=3072 K=1024, grid 24*64=1536 (%8==0)
    k_gemm<1><<<24 * 64, 256, 0, stream>>>(gate_in, 4096, WqkvT, 1024, QKVp, 3072, nullptr,
                                           1024, 24);
    k_conv_silu<<<8192, 256, 0, stream>>>(QKVp, cwq, cwk, cwv, qn, kn, v_blc);
    // delta rule
    k_delta_chunk<<<1024, 256, 0, stream>>>(qn, kn, v_blc, beta, u_buf, w_buf, locb, kT_buf);
    k_scan<<<256, 256, 0, stream>>>(qn, u_buf, w_buf, locb, kT_buf, gate_in);
    // FIR paths
    k_fir<<<dim3(32, 4, 4), 256, 0, stream>>>(v_blc, fir_s_w, fir_l_w, gate_in);
    // fusion MLP: M=8192 N=2048 K=4096, grid 16*64=1024
    k_gemm<2><<<16 * 64, 256, 0, stream>>>(gate_in, 4096, Wf1T, 4096, hid, 2048, b_f1,
                                           4096, 16);
    // fuse2: skinny K-split kernel, grid (64 m-tiles, 4 k-quarters)
    k_fuse2<<<dim3(64, 4), 256, 0, stream>>>(hid, Wf2Tp, logits4);
    k_gate<<<8192, 256, 0, stream>>>(logits4, b_f2, log_tau, norm_w, gate_in, v_blc, o_norm);
    // output projection: M=8192 N=1024 K=1024, grid 8*64=512
    k_gemm<0><<<8 * 64, 256, 0, stream>>>(o_norm, 1024, WoT, 1024, (float*)d_out, 1024, nullptr,
                                          1024, 8);
}